// Round 1
// baseline (4220.005 us; speedup 1.0000x reference)
//
#include <hip/hip_runtime.h>
#include <hip/hip_bf16.h>
#include <math.h>

// SimpleRNN: B=64, T=512, IN=512, UNITS=512, fp32.
// Phase 1: xw = x @ W_in + b  -> written into d_out[b][t][u] (in-place reuse).
// Phase 2: cooperative scan kernel, 256 blocks = 32 groups x 8 blocks.
//   group g owns batches {2g, 2g+1}; block j of group owns columns [64j, 64j+64).
//   W_rec column-slice (512x64 fp32 = 128 KB) lives in LDS for the whole kernel.
//   Per step: partial dots (k split 4-way across waves) -> LDS reduce -> tanh ->
//   write h_t into d_out (overwriting xw) -> 8-block group barrier via counter.

#define B_ 64
#define T_ 512
#define U_ 512

// ---------------- Kernel A: xw = x @ W_in + bias ----------------
// M = B*T = 32768, K = 512, N = 512. Tiles: 128x128x16, 256 threads, 8x8/thread.
__global__ __launch_bounds__(256)
void rnn_inproj_gemm(const float* __restrict__ X, const float* __restrict__ Win,
                     const float* __restrict__ bias, float* __restrict__ out) {
    __shared__ float As[16][128];  // [k][m]
    __shared__ float Bs[16][128];  // [k][n]

    const int m0 = blockIdx.x * 128;
    const int n0 = blockIdx.y * 128;
    const int tid = threadIdx.x;
    const int tx = tid & 15;       // 0..15 -> n
    const int ty = tid >> 4;       // 0..15 -> m

    float acc[8][8];
#pragma unroll
    for (int i = 0; i < 8; ++i)
#pragma unroll
        for (int j = 0; j < 8; ++j) acc[i][j] = 0.f;

    for (int k0 = 0; k0 < 512; k0 += 16) {
        // Load A tile: 128 rows x 16 cols = 512 float4; 2 per thread. Transpose into As[k][m].
#pragma unroll
        for (int i = 0; i < 2; ++i) {
            int li = tid * 2 + i;              // 0..511
            int row = li >> 2;                 // 0..127
            int c4 = li & 3;                   // which float4 in the 16-wide row
            float4 v = *(const float4*)&X[(size_t)(m0 + row) * 512 + k0 + c4 * 4];
            As[c4 * 4 + 0][row] = v.x;
            As[c4 * 4 + 1][row] = v.y;
            As[c4 * 4 + 2][row] = v.z;
            As[c4 * 4 + 3][row] = v.w;
        }
        // Load B tile: 16 rows x 128 cols = 512 float4; 2 per thread.
#pragma unroll
        for (int i = 0; i < 2; ++i) {
            int li = tid * 2 + i;              // 0..511
            int row = li >> 5;                 // 0..15
            int c4 = li & 31;                  // float4 within 128-wide row
            float4 v = *(const float4*)&Win[(size_t)(k0 + row) * 512 + n0 + c4 * 4];
            *(float4*)&Bs[row][c4 * 4] = v;
        }
        __syncthreads();

#pragma unroll
        for (int k = 0; k < 16; ++k) {
            float a[8], b[8];
            *(float4*)&a[0] = *(float4*)&As[k][ty * 8];
            *(float4*)&a[4] = *(float4*)&As[k][ty * 8 + 4];
            *(float4*)&b[0] = *(float4*)&Bs[k][tx * 8];
            *(float4*)&b[4] = *(float4*)&Bs[k][tx * 8 + 4];
#pragma unroll
            for (int i = 0; i < 8; ++i)
#pragma unroll
                for (int j = 0; j < 8; ++j) acc[i][j] += a[i] * b[j];
        }
        __syncthreads();
    }

    // Epilogue: add bias, store.
#pragma unroll
    for (int i = 0; i < 8; ++i) {
        int m = m0 + ty * 8 + i;
#pragma unroll
        for (int j = 0; j < 8; j += 4) {
            int n = n0 + tx * 8 + j;
            float4 bv = *(const float4*)&bias[n];
            float4 o;
            o.x = acc[i][j + 0] + bv.x;
            o.y = acc[i][j + 1] + bv.y;
            o.z = acc[i][j + 2] + bv.z;
            o.w = acc[i][j + 3] + bv.w;
            *(float4*)&out[(size_t)m * 512 + n] = o;
        }
    }
}

// ---------------- Kernel B: the recurrent scan ----------------

__device__ __forceinline__ float lane_bcast(float v, int l) {
    return __int_as_float(__builtin_amdgcn_readlane(__float_as_int(v), l));
}

__global__ __launch_bounds__(512, 1)
void rnn_scan(const float* __restrict__ Wrec, float* __restrict__ out,
              unsigned* __restrict__ cnt) {
    __shared__ float Wl[512][64];      // 128 KB: W_rec[:, u0:u0+64]
    __shared__ float part[4][2][64];   // 2 KB: partial dots [ksplit][batch][u]

    const int bid = blockIdx.x;
    // Group mapping keeps all 8 blocks of a group on the same blockIdx%8 residue
    // (same XCD under round-robin placement) for L2-local h exchange.
    const int xcd = bid & 7;
    const int r = bid >> 3;        // 0..31
    const int slot = r >> 3;       // 0..3
    const int j = r & 7;           // block-within-group: column slice
    const int g = xcd + 8 * slot;  // group 0..31

    const int u0 = j * 64;
    const int tid = threadIdx.x;
    const int lane = tid & 63;
    const int w = tid >> 6;        // wave 0..7
    const int ks = w >> 1;         // k-split 0..3 (each 128 k's)
    const int b = w & 1;           // batch within group
    const int bb = 2 * g + b;

    // Load W_rec column slice into LDS (once).
    for (int i = tid; i < 512 * 16; i += 512) {
        int k = i >> 4;
        int c4 = i & 15;
        float4 v = *(const float4*)&Wrec[(size_t)k * 512 + u0 + c4 * 4];
        *(float4*)&Wl[k][c4 * 4] = v;
    }
    __syncthreads();

    unsigned* myc = cnt + g * 16;  // 64B-spaced counters

    // Pointers for this thread's roles.
    const int kb = ks * 128;
    float* const rowbase = out + (size_t)bb * T_ * U_;           // h/xw rows for batch bb

    // Reduce-role mapping (tid < 128): batch b2, column u0+u.
    const int b2 = tid >> 6;
    const int u = tid & 63;
    float* const predptr = out + ((size_t)(2 * g + b2) * T_) * U_ + u0 + u;

    for (int t = 0; t < T_; ++t) {
        // Prefetch xw for this step (stable data from kernel A; hidden under compute).
        float xwv = 0.f;
        if (tid < 128) xwv = predptr[(size_t)t * U_];

        // Load h_{t-1} chunk into registers (coalesced; peers' slices fresh via barrier).
        float hr0, hr1;
        if (t == 0) {
            hr0 = 0.f; hr1 = 0.f;
        } else {
            const float* hp = rowbase + (size_t)(t - 1) * U_ + kb;
            hr0 = hp[lane];
            hr1 = hp[64 + lane];
        }

        // Partial dot over 128 k's: h broadcast via readlane (VALU), W from LDS (DS pipe).
        float a0 = 0.f, a1 = 0.f, a2 = 0.f, a3 = 0.f;
        if (t == 0) {
            // h_{-1} = 0 -> skip the dot entirely.
        } else {
#pragma unroll
            for (int q = 0; q < 64; q += 4) {
                a0 += lane_bcast(hr0, q + 0) * Wl[kb + q + 0][lane];
                a1 += lane_bcast(hr0, q + 1) * Wl[kb + q + 1][lane];
                a2 += lane_bcast(hr0, q + 2) * Wl[kb + q + 2][lane];
                a3 += lane_bcast(hr0, q + 3) * Wl[kb + q + 3][lane];
            }
#pragma unroll
            for (int q = 0; q < 64; q += 4) {
                a0 += lane_bcast(hr1, q + 0) * Wl[kb + 64 + q + 0][lane];
                a1 += lane_bcast(hr1, q + 1) * Wl[kb + 64 + q + 1][lane];
                a2 += lane_bcast(hr1, q + 2) * Wl[kb + 64 + q + 2][lane];
                a3 += lane_bcast(hr1, q + 3) * Wl[kb + 64 + q + 3][lane];
            }
        }
        part[ks][b][lane] = (a0 + a1) + (a2 + a3);
        __syncthreads();

        // Reduce 4 partials, add xw, tanh, write h_t (overwrites xw in d_out).
        if (tid < 128) {
            float s = part[0][b2][u] + part[1][b2][u] + part[2][b2][u] + part[3][b2][u];
            predptr[(size_t)t * U_] = tanhf(xwv + s);
        }
        __syncthreads();

        // 8-block group barrier (monotonic counter, agent scope).
        if (tid == 0) {
            __threadfence();                     // make our h_t slice visible
            atomicAdd(myc, 1u);                  // device-scope arrive
            const unsigned target = 8u * (t + 1);
            while (__hip_atomic_load(myc, __ATOMIC_ACQUIRE, __HIP_MEMORY_SCOPE_AGENT) < target) {
                __builtin_amdgcn_s_sleep(8);
            }
        }
        __syncthreads();
    }
}

extern "C" void kernel_launch(void* const* d_in, const int* in_sizes, int n_in,
                              void* d_out, int out_size, void* d_ws, size_t ws_size,
                              hipStream_t stream) {
    const float* x    = (const float*)d_in[0];
    const float* Win  = (const float*)d_in[1];
    const float* Wrec = (const float*)d_in[2];
    const float* bias = (const float*)d_in[3];
    float* out = (float*)d_out;

    // Zero the 32 group-barrier counters (d_ws is re-poisoned 0xAA before every call).
    hipMemsetAsync(d_ws, 0, 2048, stream);

    dim3 gA(256, 4), bA(256);
    rnn_inproj_gemm<<<gA, bA, 0, stream>>>(x, Win, bias, out);

    unsigned* cnt = (unsigned*)d_ws;
    void* args[] = { (void*)&Wrec, (void*)&out, (void*)&cnt };
    hipLaunchCooperativeKernel((const void*)rnn_scan, dim3(256), dim3(512), args, 0, stream);
}